// Round 1
// baseline (119.165 us; speedup 1.0000x reference)
//
#include <hip/hip_runtime.h>
#include <hip/hip_bf16.h>

#define N_NODES 100000
#define DEGREE 32
#define N_PAIRS 8192
#define FEAT 9
#define HID 20
#define NOUT 15
#define FPAD 16  // padded row stride (elements) for bf16 featb and t tables

#define NPB 28   // nodes per block in K1 (28*9 = 252 active lanes of 256)
#define PPB 8    // pairs per block in K2 (8*30 = 240 active lanes of 256)

// ---------------------------------------------------------------------------
// K0: prep — convert feat [N][9] fp32 -> featb [N][16] bf16 (32B-aligned rows).
//   Aligned 32B rows make every K1 neighbor gather exactly one L2 transaction
//   and shrink the gathered footprint to 3.2 MB (fully L2-resident per XCD).
// ---------------------------------------------------------------------------
__global__ __launch_bounds__(256) void k_prep(
    const float* __restrict__ feat, __hip_bfloat16* __restrict__ featb) {
  int e = blockIdx.x * 256 + threadIdx.x;
  if (e < N_NODES * FPAD) {
    int row = e >> 4;
    int col = e & (FPAD - 1);
    float v = (col < FEAT) ? feat[row * FEAT + col] : 0.f;
    featb[e] = __float2bfloat16(v);
  }
}

// ---------------------------------------------------------------------------
// K1: fused enc1-mean + node MLP. t stored bf16, stride-16 rows (32B aligned).
//   phase 1: thread (node, j): adj row via 8x int4 (broadcast within the
//            9-lane group), 32 scattered bf16 feat-row gathers (18B inside one
//            aligned 32B segment each) -> sComb in LDS. Self feat stays fp32.
//   phase 2: (node, i): h1[i] = relu(W1[i] . comb)
//   phase 3: (node, d): t[n,d] = W2[d] . h1   (linear; relu comes after the
//            enc2 mean) -> global t_ws (bf16, stride FPAD; pad slot unused).
// ---------------------------------------------------------------------------
__global__ __launch_bounds__(256) void k_node_all(
    const int* __restrict__ adj,
    const float* __restrict__ feat,
    const __hip_bfloat16* __restrict__ featb,
    const float* __restrict__ W1,   // [HID][2*FEAT]
    const float* __restrict__ W2,   // [NOUT][HID]
    __hip_bfloat16* __restrict__ t_ws) {
  __shared__ float sW1[HID * 2 * FEAT];   // 360
  __shared__ float sW2[NOUT * HID];       // 300
  __shared__ float sComb[NPB][2 * FEAT];  // 28 x 18
  __shared__ float sH[NPB][HID];          // 28 x 20

  int tid = threadIdx.x;
  for (int i = tid; i < HID * 2 * FEAT; i += 256) sW1[i] = W1[i];
  for (int i = tid; i < NOUT * HID; i += 256) sW2[i] = W2[i];

  int base = blockIdx.x * NPB;

  // phase 1: [self feat (fp32) | neighbor mean (bf16 gathers)] -> sComb
  if (tid < NPB * FEAT) {
    int nl = tid / FEAT;
    int j = tid - nl * FEAT;
    int n = base + nl;
    if (n < N_NODES) {
      const int4* arow4 = (const int4*)(adj + n * DEGREE);  // 128B-aligned
      float s = 0.f;
#pragma unroll
      for (int c = 0; c < DEGREE / 4; ++c) {
        int4 a4 = arow4[c];
        s += __bfloat162float(featb[a4.x * FPAD + j]);
        s += __bfloat162float(featb[a4.y * FPAD + j]);
        s += __bfloat162float(featb[a4.z * FPAD + j]);
        s += __bfloat162float(featb[a4.w * FPAD + j]);
      }
      sComb[nl][j] = feat[n * FEAT + j];  // self stays fp32 (contiguous read)
      sComb[nl][FEAT + j] = s * (1.0f / DEGREE);
    }
  }
  __syncthreads();

  // phase 2: h1 = relu(W1 @ comb), one thread per (node, hid)
  for (int idx = tid; idx < NPB * HID; idx += 256) {
    int nl = idx / HID;
    int i = idx - nl * HID;
    if (base + nl < N_NODES) {
      float acc = 0.f;
#pragma unroll
      for (int j = 0; j < 2 * FEAT; ++j) acc += sW1[i * 2 * FEAT + j] * sComb[nl][j];
      sH[nl][i] = fmaxf(acc, 0.f);
    }
  }
  __syncthreads();

  // phase 3: t = W2 @ h1 (linear), one thread per (node, out)
  for (int idx = tid; idx < NPB * NOUT; idx += 256) {
    int nl = idx / NOUT;
    int d = idx - nl * NOUT;
    int n = base + nl;
    if (n < N_NODES) {
      float acc = 0.f;
#pragma unroll
      for (int i = 0; i < HID; ++i) acc += sW2[d * HID + i] * sH[nl][i];
      t_ws[n * FPAD + d] = __float2bfloat16(acc);
    }
  }
}

// ---------------------------------------------------------------------------
// K2: fused enc2 endpoint aggregation + pair MLP. t read as bf16, stride-16
//   rows: the 15-lane group's 30B gather sits inside one aligned 32B segment.
//   phase 1: thread (pair, side, d) gathers 33 t-values -> e = relu(mean) in
//            LDS, concat order [side0 | side1].
//   phase 2: (pair, i): h[i] = relu(fc1[i] . e + b1[i])
//   phase 3: (pair): out = relu(fc2 . h + b2) -> global (fp32).
// ---------------------------------------------------------------------------
__global__ __launch_bounds__(256) void k_pair_all(
    const int* __restrict__ to_pred,
    const int* __restrict__ adj,
    const __hip_bfloat16* __restrict__ t_ws,
    const float* __restrict__ fc1_w,  // [15][30]
    const float* __restrict__ fc1_b,  // [15]
    const float* __restrict__ fc2_w,  // [1][15]
    const float* __restrict__ fc2_b,  // [1]
    float* __restrict__ out) {
  __shared__ float s1[15 * 30];
  __shared__ float b1v[15];
  __shared__ float s2v[15];
  __shared__ float b2v;
  __shared__ float sE[PPB][30];
  __shared__ float sHh[PPB][15];

  int tid = threadIdx.x;
  for (int i = tid; i < 15 * 30; i += 256) s1[i] = fc1_w[i];
  if (tid < 15) {
    b1v[tid] = fc1_b[tid];
    s2v[tid] = fc2_w[tid];
  }
  if (tid == 0) b2v = fc2_b[0];

  int pbase = blockIdx.x * PPB;

  // phase 1: endpoint aggregate (self + 32 neighbors of t, then relu(mean))
  if (tid < PPB * 30) {
    int pl = tid / 30;
    int slot = tid - pl * 30;
    int side = slot / 15;
    int d = slot - side * 15;
    int p = pbase + pl;                 // N_PAIRS % PPB == 0, always in range
    int node = to_pred[2 * p + side];
    const int4* arow4 = (const int4*)(adj + node * DEGREE);
    float s = __bfloat162float(t_ws[node * FPAD + d]);  // gcn=True self term
#pragma unroll
    for (int c = 0; c < DEGREE / 4; ++c) {
      int4 a4 = arow4[c];
      s += __bfloat162float(t_ws[a4.x * FPAD + d]);
      s += __bfloat162float(t_ws[a4.y * FPAD + d]);
      s += __bfloat162float(t_ws[a4.z * FPAD + d]);
      s += __bfloat162float(t_ws[a4.w * FPAD + d]);
    }
    sE[pl][slot] = fmaxf(s * (1.0f / (DEGREE + 1)), 0.f);
  }
  __syncthreads();

  // phase 2: h = relu(fc1 @ e + b1), one thread per (pair, i)
  if (tid < PPB * 15) {
    int pl = tid / 15;
    int i = tid - pl * 15;
    float acc = b1v[i];
#pragma unroll
    for (int j = 0; j < 30; ++j) acc += s1[i * 30 + j] * sE[pl][j];
    sHh[pl][i] = fmaxf(acc, 0.f);
  }
  __syncthreads();

  // phase 3: out = relu(fc2 @ h + b2), one thread per pair
  if (tid < PPB) {
    float acc = b2v;
#pragma unroll
    for (int i = 0; i < 15; ++i) acc += s2v[i] * sHh[tid][i];
    out[pbase + tid] = fmaxf(acc, 0.f);
  }
}

// ---------------------------------------------------------------------------
extern "C" void kernel_launch(void* const* d_in, const int* in_sizes, int n_in,
                              void* d_out, int out_size, void* d_ws,
                              size_t ws_size, hipStream_t stream) {
  const int* to_pred = (const int*)d_in[0];
  const int* adj     = (const int*)d_in[1];
  const float* feat  = (const float*)d_in[2];
  const float* W1    = (const float*)d_in[3];
  const float* W2    = (const float*)d_in[4];
  const float* fc1_w = (const float*)d_in[5];
  const float* fc1_b = (const float*)d_in[6];
  const float* fc2_w = (const float*)d_in[7];
  const float* fc2_b = (const float*)d_in[8];
  float* out         = (float*)d_out;

  // workspace layout: featb [100000][16] bf16 (3.2 MB) | t [100000][16] bf16 (3.2 MB)
  __hip_bfloat16* featb = (__hip_bfloat16*)d_ws;
  __hip_bfloat16* t_ws  = featb + (size_t)N_NODES * FPAD;

  int grid0 = (N_NODES * FPAD + 255) / 256;  // 6250
  k_prep<<<grid0, 256, 0, stream>>>(feat, featb);

  int grid1 = (N_NODES + NPB - 1) / NPB;   // 3572
  k_node_all<<<grid1, 256, 0, stream>>>(adj, feat, featb, W1, W2, t_ws);

  int grid2 = N_PAIRS / PPB;               // 1024
  k_pair_all<<<grid2, 256, 0, stream>>>(to_pred, adj, t_ws, fc1_w, fc1_b,
                                        fc2_w, fc2_b, out);
}